// Round 6
// baseline (1564.573 us; speedup 1.0000x reference)
//
#include <hip/hip_runtime.h>

#define NB    131072
#define EPB   8      // batch elements per block
#define NTILE 6      // M-tiles: 2 tokens x 8 elems = 16 rows
#define SEQP  12     // 11 tokens + 1 pad
#define SXW   36     // sX row stride (f32)
#define SQW2  66     // sQ row stride (u32): q/ctx/h packed [0..31], k bf16 [32..47], v bf16 [48..63], pad

// ws layout (u16 units), per transformer block tb (stride WS_U16_PER_TB):
//   qkv hi @0      [6][64][8]   qkv lo @3072
//   wo  hi @6144   [2][64][8]   wo  lo @7168
//   w1  hi @8192   [8][64][8]   w1  lo @12288
//   w2  hi @16384  [4][2][64][8] w2 lo @20480
#define WS_U16_PER_TB 24576
#define WS_REQ_BYTES  (2 * WS_U16_PER_TB * 2)   // 98304 B

typedef short    bf16x8 __attribute__((ext_vector_type(8)));
typedef float    f32x4  __attribute__((ext_vector_type(4)));
typedef unsigned u32x8  __attribute__((ext_vector_type(8)));
typedef unsigned short u16;

struct Params {
  const float *x, *w_feat, *b_feat, *cls;
  const float *in_w[2], *in_b[2], *out_w[2], *out_b[2];
  const float *ln_a_g[2], *ln_a_b[2];
  const float *w1[2], *b1[2], *w2[2], *b2[2];
  const float *ln_b_g[2], *ln_b_b[2];
  const float *clf_w, *clf_b;
  float *out;
};

__device__ __forceinline__ float bf2f(u16 h){ return __uint_as_float(((unsigned)h)<<16); }
__device__ __forceinline__ u16 f2bf(float f){
  unsigned u = __float_as_uint(f);
  u += 0x7fffu + ((u>>16)&1u);          // RNE
  return (u16)(u>>16);
}
// truncation split: a ~= hi + lo, residual <= 2^-16 |a| (lo captures hi's trunc error)
__device__ __forceinline__ void split8t(const float* p, bf16x8& hi, bf16x8& lo){
  #pragma unroll
  for (int j = 0; j < 8; ++j) {
    float a = p[j];
    unsigned u = __float_as_uint(a);
    hi[j] = (short)(u >> 16);
    float r = a - __uint_as_float(u & 0xffff0000u);
    lo[j] = (short)(__float_as_uint(r) >> 16);
  }
}
// pack f32 -> (hi16<<16)|lo16 in one u32
__device__ __forceinline__ unsigned packsplit(float a){
  unsigned u  = __float_as_uint(a);
  unsigned uh = u & 0xffff0000u;
  float    r  = a - __uint_as_float(uh);
  return uh | (__float_as_uint(r) >> 16);
}
__device__ __forceinline__ float unpack_f32(unsigned p){
  return __uint_as_float(p & 0xffff0000u) + __uint_as_float(p << 16);
}
__device__ __forceinline__ void frag_from_packed(u32x8 p, bf16x8& hi, bf16x8& lo){
  #pragma unroll
  for (int j = 0; j < 8; ++j) { hi[j] = (short)(p[j] >> 16); lo[j] = (short)(p[j] & 0xffffu); }
}
// RNE split (weights fallback path only)
__device__ __forceinline__ void split8(const float* p, bf16x8& hi, bf16x8& lo){
  #pragma unroll
  for (int j = 0; j < 8; ++j) {
    float a = p[j];
    u16 h = f2bf(a);
    hi[j] = (short)h;
    lo[j] = (short)f2bf(a - bf2f(h));
  }
}
// split-precision MFMA: acc += A*B, A=ah+al, B=bh+bl (drops al*bl ~ 2^-17)
__device__ __forceinline__ f32x4 mfma3(bf16x8 ah, bf16x8 al, bf16x8 bh, bf16x8 bl, f32x4 acc){
  acc = __builtin_amdgcn_mfma_f32_16x16x32_bf16(ah, bl, acc, 0,0,0);
  acc = __builtin_amdgcn_mfma_f32_16x16x32_bf16(al, bh, acc, 0,0,0);
  acc = __builtin_amdgcn_mfma_f32_16x16x32_bf16(ah, bh, acc, 0,0,0);
  return acc;
}
__device__ __forceinline__ bf16x8 ld8(const u16* p){ return *reinterpret_cast<const bf16x8*>(p); }
// tanh-form GELU (max abs err ~5e-4 vs exact erf form)
__device__ __forceinline__ float gelu_fast(float v){
  float y = 0.7978845608028654f * v * (1.f + 0.044715f * v * v);
  float e = __expf(2.f * y);
  float th = 1.f - 2.f * __builtin_amdgcn_rcpf(e + 1.f);
  return 0.5f * v * (1.f + th);
}

// ---------- prep: pre-split weights into per-lane B-fragment layout ----------
__global__ void OptimusPrime_prep(Params P, u16* ws)
{
  const int tb = blockIdx.x;
  u16* b = ws + tb * WS_U16_PER_TB;
  for (int idx = threadIdx.x; idx < 12288; idx += 256) {
    float v; int hiOff, loOff;
    if (idx < 3072) {                       // qkv  [6][64][8], K=32
      int nt = idx >> 9, lane = (idx >> 3) & 63, j = idx & 7;
      v = P.in_w[tb][(nt*16 + (lane&15))*32 + (lane>>4)*8 + j];
      hiOff = idx; loOff = 3072 + idx;
    } else if (idx < 4096) {                // wo   [2][64][8], K=32
      int m = idx - 3072;
      int nt = m >> 9, lane = (m >> 3) & 63, j = m & 7;
      v = P.out_w[tb][(nt*16 + (lane&15))*32 + (lane>>4)*8 + j];
      hiOff = 6144 + m; loOff = 7168 + m;
    } else if (idx < 8192) {                // w1   [8][64][8], K=32
      int m = idx - 4096;
      int nt = m >> 9, lane = (m >> 3) & 63, j = m & 7;
      v = P.w1[tb][(nt*16 + (lane&15))*32 + (lane>>4)*8 + j];
      hiOff = 8192 + m; loOff = 12288 + m;
    } else {                                // w2   [4][2][64][8], K=128
      int m = idx - 8192;
      int kt = m >> 10, nt = (m >> 9) & 1, lane = (m >> 3) & 63, j = m & 7;
      v = P.w2[tb][(nt*16 + (lane&15))*128 + kt*32 + (lane>>4)*8 + j];
      hiOff = 16384 + m; loOff = 20480 + m;
    }
    u16 h = f2bf(v);
    b[hiOff] = h;
    b[loOff] = f2bf(v - bf2f(h));
  }
}

// MFMA 16x16x32 bf16 layouts:
//   A-frag: a[j] = A[m=lane&15][k=(lane>>4)*8+j]
//   B-frag: b[j] = B[k=(lane>>4)*8+j][n=lane&15]
//   C/D   : acc[r] = C[row=(lane>>4)*4+r][col=lane&15]
// M-tile t covers rows m in [0,16): token s = 2t + (m>>3), elem e = m&7.

template<bool WS>
__global__ __launch_bounds__(256, 4)
void OptimusPrime_kernel(Params P, const u16* __restrict__ ws)
{
  __shared__ float    sX[SEQP][EPB][SXW];   // 13824 B : residual stream (f32)
  __shared__ unsigned sQ[SEQP][EPB][SQW2];  // 25344 B : packed q/ctx/h + bf16 k,v

  const int tid  = threadIdx.x;
  const int w    = tid >> 6;
  const int lane = tid & 63;
  const int quad = lane >> 4;
  const int l16  = lane & 15;
  const int kq   = quad * 8;
  const int base = blockIdx.x * EPB;

  const int sA  = (l16 >> 3);
  const int eA  = (l16 & 7);
  const int sC  = (quad >> 1);
  const int eC0 = (quad & 1) * 4;

  // ---------- embed ----------
  for (int i = tid; i < SEQP*EPB*32; i += 256) {
    int d = i & 31, e = (i >> 5) & 7, s = i >> 8;
    float v;
    if (s == 0 || s == 11) v = P.cls[d];
    else v = P.x[(base+e)*10 + (s-1)] * P.w_feat[(s-1)*32 + d] + P.b_feat[(s-1)*32 + d];
    sX[s][e][d] = v;
  }
  __syncthreads();

  for (int tb = 0; tb < 2; ++tb) {
    const u16* wsb = WS ? (ws + tb * WS_U16_PER_TB) : nullptr;

    // ---------- QKV projection ----------
    {
      bf16x8 bh[6], bl[6]; float bias[6];
      #pragma unroll
      for (int nt = 0; nt < 6; ++nt) {
        if (WS) {
          bh[nt] = ld8(wsb + (nt*64 + lane)*8);
          bl[nt] = ld8(wsb + 3072 + (nt*64 + lane)*8);
        } else {
          split8(P.in_w[tb] + (nt*16 + l16)*32 + kq, bh[nt], bl[nt]);
        }
        bias[nt] = P.in_b[tb][nt*16 + l16];
      }
      for (int t = w; t < NTILE; t += 4) {
        bf16x8 ah, al; split8t(&sX[2*t + sA][eA][kq], ah, al);
        #pragma unroll
        for (int nt = 0; nt < 6; ++nt) {
          f32x4 acc = {0.f,0.f,0.f,0.f};
          acc = mfma3(ah, al, bh[nt], bl[nt], acc);
          #pragma unroll
          for (int r = 0; r < 4; ++r) {
            float vv = acc[r] + bias[nt];
            unsigned* qrow = &sQ[2*t + sC][eC0 + r][0];
            if (nt < 2) {
              qrow[nt*16 + l16] = packsplit(vv);                 // q packed
            } else if (nt < 4) {
              ((u16*)qrow)[64 + (nt-2)*16 + l16] = f2bf(vv);     // k bf16
            } else {
              ((u16*)qrow)[96 + (nt-4)*16 + l16] = f2bf(vv);     // v bf16
            }
          }
        }
      }
    }
    __syncthreads();

    // ---------- attention ----------
    {
      const int e = tid >> 5, hh = (tid >> 3) & 3, qs = tid & 7;
      for (int qi = qs; qi < 11; qi += 8) {
        u32x8 qp = *reinterpret_cast<const u32x8*>(&sQ[qi][e][hh*8]);
        float qf[8];
        #pragma unroll
        for (int j = 0; j < 8; ++j) qf[j] = unpack_f32(qp[j]) * 0.35355339059f;  // 1/sqrt(8)
        float sc[11]; float l = 0.f;
        for (int ki = 0; ki < 11; ++ki) {
          const u16* rk = (const u16*)&sQ[ki][e][0];
          bf16x8 kv = ld8(rk + 64 + hh*8);
          float s = 0.f;
          #pragma unroll
          for (int j = 0; j < 8; ++j) s += qf[j] * bf2f((u16)kv[j]);
          sc[ki] = __expf(s);            // scores O(1): no max-subtraction needed
          l += sc[ki];
        }
        float inv = __builtin_amdgcn_rcpf(l);
        float cx[8] = {0,0,0,0,0,0,0,0};
        for (int ki = 0; ki < 11; ++ki) {
          const u16* rv = (const u16*)&sQ[ki][e][0];
          bf16x8 vv = ld8(rv + 96 + hh*8);
          float p = sc[ki];
          #pragma unroll
          for (int j = 0; j < 8; ++j) cx[j] += p * bf2f((u16)vv[j]);
        }
        unsigned* wq = &sQ[qi][e][hh*8];
        #pragma unroll
        for (int j = 0; j < 8; ++j) wq[j] = packsplit(cx[j] * inv);   // ctx -> q slot, packed
      }
    }
    __syncthreads();

    // ---------- out-proj + LN_a + FFN + LN_b ----------
    {
      bf16x8 woh[2], wol[2], w1h[8], w1l[8], w2h[4][2], w2l[4][2];
      float ob[2], b1v[8], b2v[2], lag[2], lab[2], lbg[2], lbb[2];
      #pragma unroll
      for (int nt = 0; nt < 2; ++nt) {
        if (WS) {
          woh[nt] = ld8(wsb + 6144 + (nt*64 + lane)*8);
          wol[nt] = ld8(wsb + 7168 + (nt*64 + lane)*8);
        } else {
          split8(P.out_w[tb] + (nt*16 + l16)*32 + kq, woh[nt], wol[nt]);
        }
        ob[nt]  = P.out_b[tb][nt*16 + l16];
        b2v[nt] = P.b2[tb][nt*16 + l16];
        lag[nt] = P.ln_a_g[tb][nt*16 + l16]; lab[nt] = P.ln_a_b[tb][nt*16 + l16];
        lbg[nt] = P.ln_b_g[tb][nt*16 + l16]; lbb[nt] = P.ln_b_b[tb][nt*16 + l16];
      }
      #pragma unroll
      for (int f8 = 0; f8 < 8; ++f8) {
        if (WS) {
          w1h[f8] = ld8(wsb + 8192  + (f8*64 + lane)*8);
          w1l[f8] = ld8(wsb + 12288 + (f8*64 + lane)*8);
        } else {
          split8(P.w1[tb] + (f8*16 + l16)*32 + kq, w1h[f8], w1l[f8]);
        }
        b1v[f8] = P.b1[tb][f8*16 + l16];
      }
      #pragma unroll
      for (int kt = 0; kt < 4; ++kt)
        #pragma unroll
        for (int nt = 0; nt < 2; ++nt) {
          if (WS) {
            w2h[kt][nt] = ld8(wsb + 16384 + ((kt*2 + nt)*64 + lane)*8);
            w2l[kt][nt] = ld8(wsb + 20480 + ((kt*2 + nt)*64 + lane)*8);
          } else {
            split8(P.w2[tb] + (nt*16 + l16)*128 + kt*32 + kq, w2h[kt][nt], w2l[kt][nt]);
          }
        }

      for (int t = w; t < NTILE; t += 4) {
        // out-projection of packed ctx
        u32x8 cp = *reinterpret_cast<const u32x8*>(&sQ[2*t + sA][eA][kq]);
        bf16x8 ah, al; frag_from_packed(cp, ah, al);
        float tt[2][4];
        #pragma unroll
        for (int nt = 0; nt < 2; ++nt) {
          f32x4 acc = {0.f,0.f,0.f,0.f};
          acc = mfma3(ah, al, woh[nt], wol[nt], acc);
          #pragma unroll
          for (int r = 0; r < 4; ++r)
            tt[nt][r] = acc[r] + ob[nt] + sX[2*t + sC][eC0 + r][nt*16 + l16];  // + residual
        }
        // LN_a
        #pragma unroll
        for (int r = 0; r < 4; ++r) {
          float s1 = tt[0][r] + tt[1][r];
          float s2 = tt[0][r]*tt[0][r] + tt[1][r]*tt[1][r];
          #pragma unroll
          for (int mk = 1; mk < 16; mk <<= 1) { s1 += __shfl_xor(s1, mk); s2 += __shfl_xor(s2, mk); }
          float mu  = s1 * (1.f/32.f);
          float var = fmaxf(s2 * (1.f/32.f) - mu*mu, 0.f);
          float rs  = rsqrtf(var + 1e-5f);
          #pragma unroll
          for (int nt = 0; nt < 2; ++nt) {
            float y = (tt[nt][r] - mu)*rs*lag[nt] + lab[nt];
            sX[2*t + sC][eC0 + r][nt*16 + l16] = y;
          }
        }
        // FFN: h halves of 64 features, packed u32 overlaying dead q/k/v cols of own tile rows
        bf16x8 xh, xl; split8t(&sX[2*t + sA][eA][kq], xh, xl);
        f32x4 ca0 = {0.f,0.f,0.f,0.f}, ca1 = {0.f,0.f,0.f,0.f};
        #pragma unroll
        for (int ht = 0; ht < 2; ++ht) {
          #pragma unroll
          for (int ntl = 0; ntl < 4; ++ntl) {
            int fi = ht*4 + ntl;
            f32x4 acc = {0.f,0.f,0.f,0.f};
            acc = mfma3(xh, xl, w1h[fi], w1l[fi], acc);
            #pragma unroll
            for (int r = 0; r < 4; ++r) {
              float v = acc[r] + b1v[fi];
              sQ[2*t + sC][eC0 + r][ntl*16 + l16] = packsplit(gelu_fast(v));
            }
          }
          #pragma unroll
          for (int kt2 = 0; kt2 < 2; ++kt2) {
            int kt = ht*2 + kt2;
            u32x8 hp = *reinterpret_cast<const u32x8*>(&sQ[2*t + sA][eA][kt2*32 + kq]);
            bf16x8 hhf, hlf; frag_from_packed(hp, hhf, hlf);
            ca0 = mfma3(hhf, hlf, w2h[kt][0], w2l[kt][0], ca0);
            ca1 = mfma3(hhf, hlf, w2h[kt][1], w2l[kt][1], ca1);
          }
        }
        #pragma unroll
        for (int nt = 0; nt < 2; ++nt) {
          f32x4 ca = nt ? ca1 : ca0;
          #pragma unroll
          for (int r = 0; r < 4; ++r)
            tt[nt][r] = ca[r] + b2v[nt] + sX[2*t + sC][eC0 + r][nt*16 + l16];  // + residual
        }
        // LN_b
        #pragma unroll
        for (int r = 0; r < 4; ++r) {
          float s1 = tt[0][r] + tt[1][r];
          float s2 = tt[0][r]*tt[0][r] + tt[1][r]*tt[1][r];
          #pragma unroll
          for (int mk = 1; mk < 16; mk <<= 1) { s1 += __shfl_xor(s1, mk); s2 += __shfl_xor(s2, mk); }
          float mu  = s1 * (1.f/32.f);
          float var = fmaxf(s2 * (1.f/32.f) - mu*mu, 0.f);
          float rs  = rsqrtf(var + 1e-5f);
          #pragma unroll
          for (int nt = 0; nt < 2; ++nt) {
            float y = (tt[nt][r] - mu)*rs*lbg[nt] + lbb[nt];
            sX[2*t + sC][eC0 + r][nt*16 + l16] = y;
          }
        }
      }
    }
    __syncthreads();
  }

  // ---------- classifier: out[b] = sX[0][e][:] . clf_w + clf_b ----------
  if (w == 0) {
    int e = lane >> 3, dq = lane & 7;
    float p = 0.f;
    #pragma unroll
    for (int j = 0; j < 4; ++j)
      p += sX[0][e][dq*4 + j] * P.clf_w[dq*4 + j];
    p += __shfl_xor(p, 1);
    p += __shfl_xor(p, 2);
    p += __shfl_xor(p, 4);
    if (dq == 0)
      P.out[base + e] = p + P.clf_b[0];
  }
}

extern "C" void kernel_launch(void* const* d_in, const int* in_sizes, int n_in,
                              void* d_out, int out_size, void* d_ws, size_t ws_size,
                              hipStream_t stream)
{
  Params P;
  P.x        = (const float*)d_in[0];
  P.w_feat   = (const float*)d_in[1];
  P.b_feat   = (const float*)d_in[2];
  P.cls      = (const float*)d_in[3];
  P.in_w[0]  = (const float*)d_in[4];   P.in_b[0]  = (const float*)d_in[5];
  P.out_w[0] = (const float*)d_in[6];   P.out_b[0] = (const float*)d_in[7];
  P.ln_a_g[0]= (const float*)d_in[8];   P.ln_a_b[0]= (const float*)d_in[9];
  P.w1[0]    = (const float*)d_in[10];  P.b1[0]    = (const float*)d_in[11];
  P.w2[0]    = (const float*)d_in[12];  P.b2[0]    = (const float*)d_in[13];
  P.ln_b_g[0]= (const float*)d_in[14];  P.ln_b_b[0]= (const float*)d_in[15];
  P.in_w[1]  = (const float*)d_in[16];  P.in_b[1]  = (const float*)d_in[17];
  P.out_w[1] = (const float*)d_in[18];  P.out_b[1] = (const float*)d_in[19];
  P.ln_a_g[1]= (const float*)d_in[20];  P.ln_a_b[1]= (const float*)d_in[21];
  P.w1[1]    = (const float*)d_in[22];  P.b1[1]    = (const float*)d_in[23];
  P.w2[1]    = (const float*)d_in[24];  P.b2[1]    = (const float*)d_in[25];
  P.ln_b_g[1]= (const float*)d_in[26];  P.ln_b_b[1]= (const float*)d_in[27];
  P.clf_w    = (const float*)d_in[28];  P.clf_b    = (const float*)d_in[29];
  P.out      = (float*)d_out;

  dim3 grid(NB / EPB), block(256);
  if (ws_size >= (size_t)WS_REQ_BYTES) {
    u16* ws = (u16*)d_ws;
    hipLaunchKernelGGL(OptimusPrime_prep, dim3(2), dim3(256), 0, stream, P, ws);
    hipLaunchKernelGGL(OptimusPrime_kernel<true>, grid, block, 0, stream, P, (const u16*)ws);
  } else {
    hipLaunchKernelGGL(OptimusPrime_kernel<false>, grid, block, 0, stream, P, (const u16*)nullptr);
  }
}

// Round 7
// 1412.913 us; speedup vs baseline: 1.1073x; 1.1073x over previous
//
#include <hip/hip_runtime.h>

#define NB    131072
#define EPB   8      // batch elements per block
#define NTILE 6      // M-tiles: 2 tokens x 8 elems = 16 rows
#define SEQP  12     // 11 tokens + 1 pad
#define SXW   36     // sX row stride (f32)
#define SQW2  66     // sQ row stride (u32): q/ctx/h packed [0..31], k bf16 [32..47], v bf16 [48..63], pad

// ws layout (u16 units), per transformer block tb (stride WS_U16_PER_TB):
//   qkv hi @0      [6][64][8]   qkv lo @3072
//   wo  hi @6144   [2][64][8]   wo  lo @7168
//   w1  hi @8192   [8][64][8]   w1  lo @12288
//   w2  hi @16384  [4][2][64][8] w2 lo @20480
#define WS_U16_PER_TB 24576
#define WS_REQ_BYTES  (2 * WS_U16_PER_TB * 2)   // 98304 B

typedef short    bf16x8 __attribute__((ext_vector_type(8)));
typedef float    f32x4  __attribute__((ext_vector_type(4)));
typedef unsigned u32x8  __attribute__((ext_vector_type(8)));
typedef unsigned short u16;

struct Params {
  const float *x, *w_feat, *b_feat, *cls;
  const float *in_w[2], *in_b[2], *out_w[2], *out_b[2];
  const float *ln_a_g[2], *ln_a_b[2];
  const float *w1[2], *b1[2], *w2[2], *b2[2];
  const float *ln_b_g[2], *ln_b_b[2];
  const float *clf_w, *clf_b;
  float *out;
};

__device__ __forceinline__ float bf2f(u16 h){ return __uint_as_float(((unsigned)h)<<16); }
__device__ __forceinline__ u16 f2bf(float f){
  unsigned u = __float_as_uint(f);
  u += 0x7fffu + ((u>>16)&1u);          // RNE
  return (u16)(u>>16);
}
// truncation split: a ~= hi + lo, residual <= 2^-16 |a|
__device__ __forceinline__ void split8t(const float* p, bf16x8& hi, bf16x8& lo){
  #pragma unroll
  for (int j = 0; j < 8; ++j) {
    float a = p[j];
    unsigned u = __float_as_uint(a);
    hi[j] = (short)(u >> 16);
    float r = a - __uint_as_float(u & 0xffff0000u);
    lo[j] = (short)(__float_as_uint(r) >> 16);
  }
}
// pack f32 -> (hi16<<16)|lo16 in one u32
__device__ __forceinline__ unsigned packsplit(float a){
  unsigned u  = __float_as_uint(a);
  unsigned uh = u & 0xffff0000u;
  float    r  = a - __uint_as_float(uh);
  return uh | (__float_as_uint(r) >> 16);
}
__device__ __forceinline__ float unpack_f32(unsigned p){
  return __uint_as_float(p & 0xffff0000u) + __uint_as_float(p << 16);
}
__device__ __forceinline__ void frag_from_packed(u32x8 p, bf16x8& hi, bf16x8& lo){
  #pragma unroll
  for (int j = 0; j < 8; ++j) { hi[j] = (short)(p[j] >> 16); lo[j] = (short)(p[j] & 0xffffu); }
}
// RNE split (weights fallback path only)
__device__ __forceinline__ void split8(const float* p, bf16x8& hi, bf16x8& lo){
  #pragma unroll
  for (int j = 0; j < 8; ++j) {
    float a = p[j];
    u16 h = f2bf(a);
    hi[j] = (short)h;
    lo[j] = (short)f2bf(a - bf2f(h));
  }
}
// split-precision MFMA: acc += A*B, A=ah+al, B=bh+bl (drops al*bl ~ 2^-17)
__device__ __forceinline__ f32x4 mfma3(bf16x8 ah, bf16x8 al, bf16x8 bh, bf16x8 bl, f32x4 acc){
  acc = __builtin_amdgcn_mfma_f32_16x16x32_bf16(ah, bl, acc, 0,0,0);
  acc = __builtin_amdgcn_mfma_f32_16x16x32_bf16(al, bh, acc, 0,0,0);
  acc = __builtin_amdgcn_mfma_f32_16x16x32_bf16(ah, bh, acc, 0,0,0);
  return acc;
}
__device__ __forceinline__ bf16x8 ld8(const u16* p){ return *reinterpret_cast<const bf16x8*>(p); }
// tanh-form GELU (max abs err ~5e-4 vs exact erf form)
__device__ __forceinline__ float gelu_fast(float v){
  float y = 0.7978845608028654f * v * (1.f + 0.044715f * v * v);
  float e = __expf(2.f * y);
  float th = 1.f - 2.f * __builtin_amdgcn_rcpf(e + 1.f);
  return 0.5f * v * (1.f + th);
}

// ---------- prep: pre-split weights into per-lane B-fragment layout ----------
__global__ void OptimusPrime_prep(Params P, u16* ws)
{
  const int tb = blockIdx.x;
  u16* b = ws + tb * WS_U16_PER_TB;
  for (int idx = threadIdx.x; idx < 12288; idx += 256) {
    float v; int hiOff, loOff;
    if (idx < 3072) {                       // qkv  [6][64][8], K=32
      int nt = idx >> 9, lane = (idx >> 3) & 63, j = idx & 7;
      v = P.in_w[tb][(nt*16 + (lane&15))*32 + (lane>>4)*8 + j];
      hiOff = idx; loOff = 3072 + idx;
    } else if (idx < 4096) {                // wo   [2][64][8], K=32
      int m = idx - 3072;
      int nt = m >> 9, lane = (m >> 3) & 63, j = m & 7;
      v = P.out_w[tb][(nt*16 + (lane&15))*32 + (lane>>4)*8 + j];
      hiOff = 6144 + m; loOff = 7168 + m;
    } else if (idx < 8192) {                // w1   [8][64][8], K=32
      int m = idx - 4096;
      int nt = m >> 9, lane = (m >> 3) & 63, j = m & 7;
      v = P.w1[tb][(nt*16 + (lane&15))*32 + (lane>>4)*8 + j];
      hiOff = 8192 + m; loOff = 12288 + m;
    } else {                                // w2   [4][2][64][8], K=128
      int m = idx - 8192;
      int kt = m >> 10, nt = (m >> 9) & 1, lane = (m >> 3) & 63, j = m & 7;
      v = P.w2[tb][(nt*16 + (lane&15))*128 + kt*32 + (lane>>4)*8 + j];
      hiOff = 16384 + m; loOff = 20480 + m;
    }
    u16 h = f2bf(v);
    b[hiOff] = h;
    b[loOff] = f2bf(v - bf2f(h));
  }
}

// MFMA 16x16x32 bf16 layouts:
//   A-frag: a[j] = A[m=lane&15][k=(lane>>4)*8+j]
//   B-frag: b[j] = B[k=(lane>>4)*8+j][n=lane&15]
//   C/D   : acc[r] = C[row=(lane>>4)*4+r][col=lane&15]
// M-tile t covers rows m in [0,16): token s = 2t + (m>>3), elem e = m&7.

template<bool WS>
__global__ __launch_bounds__(256, 3)   // 3 waves/EU: VGPR cap ~170 — rnd6 showed cap=4 (64 VGPR) spills 2.4GB to scratch
void OptimusPrime_kernel(Params P, const u16* __restrict__ ws)
{
  __shared__ float    sX[SEQP][EPB][SXW];   // 13824 B : residual stream (f32)
  __shared__ unsigned sQ[SEQP][EPB][SQW2];  // 25344 B : packed q/ctx/h + bf16 k,v

  const int tid  = threadIdx.x;
  const int w    = tid >> 6;
  const int lane = tid & 63;
  const int quad = lane >> 4;
  const int l16  = lane & 15;
  const int kq   = quad * 8;
  const int base = blockIdx.x * EPB;

  const int sA  = (l16 >> 3);
  const int eA  = (l16 & 7);
  const int sC  = (quad >> 1);
  const int eC0 = (quad & 1) * 4;

  // ---------- embed ----------
  for (int i = tid; i < SEQP*EPB*32; i += 256) {
    int d = i & 31, e = (i >> 5) & 7, s = i >> 8;
    float v;
    if (s == 0 || s == 11) v = P.cls[d];
    else v = P.x[(base+e)*10 + (s-1)] * P.w_feat[(s-1)*32 + d] + P.b_feat[(s-1)*32 + d];
    sX[s][e][d] = v;
  }
  __syncthreads();

  for (int tb = 0; tb < 2; ++tb) {
    const u16* wsb = WS ? (ws + tb * WS_U16_PER_TB) : nullptr;

    // ---------- QKV projection ----------
    {
      bf16x8 bh[6], bl[6]; float bias[6];
      #pragma unroll
      for (int nt = 0; nt < 6; ++nt) {
        if (WS) {
          bh[nt] = ld8(wsb + (nt*64 + lane)*8);
          bl[nt] = ld8(wsb + 3072 + (nt*64 + lane)*8);
        } else {
          split8(P.in_w[tb] + (nt*16 + l16)*32 + kq, bh[nt], bl[nt]);
        }
        bias[nt] = P.in_b[tb][nt*16 + l16];
      }
      for (int t = w; t < NTILE; t += 4) {
        bf16x8 ah, al; split8t(&sX[2*t + sA][eA][kq], ah, al);
        #pragma unroll
        for (int nt = 0; nt < 6; ++nt) {
          f32x4 acc = {0.f,0.f,0.f,0.f};
          acc = mfma3(ah, al, bh[nt], bl[nt], acc);
          #pragma unroll
          for (int r = 0; r < 4; ++r) {
            float vv = acc[r] + bias[nt];
            unsigned* qrow = &sQ[2*t + sC][eC0 + r][0];
            if (nt < 2) {
              qrow[nt*16 + l16] = packsplit(vv);                 // q packed
            } else if (nt < 4) {
              ((u16*)qrow)[64 + (nt-2)*16 + l16] = f2bf(vv);     // k bf16
            } else {
              ((u16*)qrow)[96 + (nt-4)*16 + l16] = f2bf(vv);     // v bf16
            }
          }
        }
      }
    }
    __syncthreads();

    // ---------- attention ----------
    {
      const int e = tid >> 5, hh = (tid >> 3) & 3, qs = tid & 7;
      for (int qi = qs; qi < 11; qi += 8) {
        u32x8 qp = *reinterpret_cast<const u32x8*>(&sQ[qi][e][hh*8]);
        float qf[8];
        #pragma unroll
        for (int j = 0; j < 8; ++j) qf[j] = unpack_f32(qp[j]) * 0.35355339059f;  // 1/sqrt(8)
        float sc[11]; float l = 0.f;
        for (int ki = 0; ki < 11; ++ki) {
          const u16* rk = (const u16*)&sQ[ki][e][0];
          bf16x8 kv = ld8(rk + 64 + hh*8);
          float s = 0.f;
          #pragma unroll
          for (int j = 0; j < 8; ++j) s += qf[j] * bf2f((u16)kv[j]);
          sc[ki] = __expf(s);            // scores O(1): no max-subtraction needed
          l += sc[ki];
        }
        float inv = __builtin_amdgcn_rcpf(l);
        float cx[8] = {0,0,0,0,0,0,0,0};
        for (int ki = 0; ki < 11; ++ki) {
          const u16* rv = (const u16*)&sQ[ki][e][0];
          bf16x8 vv = ld8(rv + 96 + hh*8);
          float p = sc[ki];
          #pragma unroll
          for (int j = 0; j < 8; ++j) cx[j] += p * bf2f((u16)vv[j]);
        }
        unsigned* wq = &sQ[qi][e][hh*8];
        #pragma unroll
        for (int j = 0; j < 8; ++j) wq[j] = packsplit(cx[j] * inv);   // ctx -> q slot, packed
      }
    }
    __syncthreads();

    // ---------- out-proj + LN_a + FFN + LN_b ----------
    {
      bf16x8 woh[2], wol[2], w1h[8], w1l[8], w2h[4][2], w2l[4][2];
      float ob[2], b1v[8], b2v[2], lag[2], lab[2], lbg[2], lbb[2];
      #pragma unroll
      for (int nt = 0; nt < 2; ++nt) {
        if (WS) {
          woh[nt] = ld8(wsb + 6144 + (nt*64 + lane)*8);
          wol[nt] = ld8(wsb + 7168 + (nt*64 + lane)*8);
        } else {
          split8(P.out_w[tb] + (nt*16 + l16)*32 + kq, woh[nt], wol[nt]);
        }
        ob[nt]  = P.out_b[tb][nt*16 + l16];
        b2v[nt] = P.b2[tb][nt*16 + l16];
        lag[nt] = P.ln_a_g[tb][nt*16 + l16]; lab[nt] = P.ln_a_b[tb][nt*16 + l16];
        lbg[nt] = P.ln_b_g[tb][nt*16 + l16]; lbb[nt] = P.ln_b_b[tb][nt*16 + l16];
      }
      #pragma unroll
      for (int f8 = 0; f8 < 8; ++f8) {
        if (WS) {
          w1h[f8] = ld8(wsb + 8192  + (f8*64 + lane)*8);
          w1l[f8] = ld8(wsb + 12288 + (f8*64 + lane)*8);
        } else {
          split8(P.w1[tb] + (f8*16 + l16)*32 + kq, w1h[f8], w1l[f8]);
        }
        b1v[f8] = P.b1[tb][f8*16 + l16];
      }
      #pragma unroll
      for (int kt = 0; kt < 4; ++kt)
        #pragma unroll
        for (int nt = 0; nt < 2; ++nt) {
          if (WS) {
            w2h[kt][nt] = ld8(wsb + 16384 + ((kt*2 + nt)*64 + lane)*8);
            w2l[kt][nt] = ld8(wsb + 20480 + ((kt*2 + nt)*64 + lane)*8);
          } else {
            split8(P.w2[tb] + (nt*16 + l16)*128 + kt*32 + kq, w2h[kt][nt], w2l[kt][nt]);
          }
        }

      for (int t = w; t < NTILE; t += 4) {
        // out-projection of packed ctx
        u32x8 cp = *reinterpret_cast<const u32x8*>(&sQ[2*t + sA][eA][kq]);
        bf16x8 ah, al; frag_from_packed(cp, ah, al);
        float tt[2][4];
        #pragma unroll
        for (int nt = 0; nt < 2; ++nt) {
          f32x4 acc = {0.f,0.f,0.f,0.f};
          acc = mfma3(ah, al, woh[nt], wol[nt], acc);
          #pragma unroll
          for (int r = 0; r < 4; ++r)
            tt[nt][r] = acc[r] + ob[nt] + sX[2*t + sC][eC0 + r][nt*16 + l16];  // + residual
        }
        // LN_a
        #pragma unroll
        for (int r = 0; r < 4; ++r) {
          float s1 = tt[0][r] + tt[1][r];
          float s2 = tt[0][r]*tt[0][r] + tt[1][r]*tt[1][r];
          #pragma unroll
          for (int mk = 1; mk < 16; mk <<= 1) { s1 += __shfl_xor(s1, mk); s2 += __shfl_xor(s2, mk); }
          float mu  = s1 * (1.f/32.f);
          float var = fmaxf(s2 * (1.f/32.f) - mu*mu, 0.f);
          float rs  = rsqrtf(var + 1e-5f);
          #pragma unroll
          for (int nt = 0; nt < 2; ++nt) {
            float y = (tt[nt][r] - mu)*rs*lag[nt] + lab[nt];
            sX[2*t + sC][eC0 + r][nt*16 + l16] = y;
          }
        }
        // FFN: h halves of 64 features, packed u32 overlaying dead q/k/v cols of own tile rows
        bf16x8 xh, xl; split8t(&sX[2*t + sA][eA][kq], xh, xl);
        f32x4 ca0 = {0.f,0.f,0.f,0.f}, ca1 = {0.f,0.f,0.f,0.f};
        #pragma unroll
        for (int ht = 0; ht < 2; ++ht) {
          #pragma unroll
          for (int ntl = 0; ntl < 4; ++ntl) {
            int fi = ht*4 + ntl;
            f32x4 acc = {0.f,0.f,0.f,0.f};
            acc = mfma3(xh, xl, w1h[fi], w1l[fi], acc);
            #pragma unroll
            for (int r = 0; r < 4; ++r) {
              float v = acc[r] + b1v[fi];
              sQ[2*t + sC][eC0 + r][ntl*16 + l16] = packsplit(gelu_fast(v));
            }
          }
          #pragma unroll
          for (int kt2 = 0; kt2 < 2; ++kt2) {
            int kt = ht*2 + kt2;
            u32x8 hp = *reinterpret_cast<const u32x8*>(&sQ[2*t + sA][eA][kt2*32 + kq]);
            bf16x8 hhf, hlf; frag_from_packed(hp, hhf, hlf);
            ca0 = mfma3(hhf, hlf, w2h[kt][0], w2l[kt][0], ca0);
            ca1 = mfma3(hhf, hlf, w2h[kt][1], w2l[kt][1], ca1);
          }
        }
        #pragma unroll
        for (int nt = 0; nt < 2; ++nt) {
          f32x4 ca = nt ? ca1 : ca0;
          #pragma unroll
          for (int r = 0; r < 4; ++r)
            tt[nt][r] = ca[r] + b2v[nt] + sX[2*t + sC][eC0 + r][nt*16 + l16];  // + residual
        }
        // LN_b
        #pragma unroll
        for (int r = 0; r < 4; ++r) {
          float s1 = tt[0][r] + tt[1][r];
          float s2 = tt[0][r]*tt[0][r] + tt[1][r]*tt[1][r];
          #pragma unroll
          for (int mk = 1; mk < 16; mk <<= 1) { s1 += __shfl_xor(s1, mk); s2 += __shfl_xor(s2, mk); }
          float mu  = s1 * (1.f/32.f);
          float var = fmaxf(s2 * (1.f/32.f) - mu*mu, 0.f);
          float rs  = rsqrtf(var + 1e-5f);
          #pragma unroll
          for (int nt = 0; nt < 2; ++nt) {
            float y = (tt[nt][r] - mu)*rs*lbg[nt] + lbb[nt];
            sX[2*t + sC][eC0 + r][nt*16 + l16] = y;
          }
        }
      }
    }
    __syncthreads();
  }

  // ---------- classifier: out[b] = sX[0][e][:] . clf_w + clf_b ----------
  if (w == 0) {
    int e = lane >> 3, dq = lane & 7;
    float p = 0.f;
    #pragma unroll
    for (int j = 0; j < 4; ++j)
      p += sX[0][e][dq*4 + j] * P.clf_w[dq*4 + j];
    p += __shfl_xor(p, 1);
    p += __shfl_xor(p, 2);
    p += __shfl_xor(p, 4);
    if (dq == 0)
      P.out[base + e] = p + P.clf_b[0];
  }
}

extern "C" void kernel_launch(void* const* d_in, const int* in_sizes, int n_in,
                              void* d_out, int out_size, void* d_ws, size_t ws_size,
                              hipStream_t stream)
{
  Params P;
  P.x        = (const float*)d_in[0];
  P.w_feat   = (const float*)d_in[1];
  P.b_feat   = (const float*)d_in[2];
  P.cls      = (const float*)d_in[3];
  P.in_w[0]  = (const float*)d_in[4];   P.in_b[0]  = (const float*)d_in[5];
  P.out_w[0] = (const float*)d_in[6];   P.out_b[0] = (const float*)d_in[7];
  P.ln_a_g[0]= (const float*)d_in[8];   P.ln_a_b[0]= (const float*)d_in[9];
  P.w1[0]    = (const float*)d_in[10];  P.b1[0]    = (const float*)d_in[11];
  P.w2[0]    = (const float*)d_in[12];  P.b2[0]    = (const float*)d_in[13];
  P.ln_b_g[0]= (const float*)d_in[14];  P.ln_b_b[0]= (const float*)d_in[15];
  P.in_w[1]  = (const float*)d_in[16];  P.in_b[1]  = (const float*)d_in[17];
  P.out_w[1] = (const float*)d_in[18];  P.out_b[1] = (const float*)d_in[19];
  P.ln_a_g[1]= (const float*)d_in[20];  P.ln_a_b[1]= (const float*)d_in[21];
  P.w1[1]    = (const float*)d_in[22];  P.b1[1]    = (const float*)d_in[23];
  P.w2[1]    = (const float*)d_in[24];  P.b2[1]    = (const float*)d_in[25];
  P.ln_b_g[1]= (const float*)d_in[26];  P.ln_b_b[1]= (const float*)d_in[27];
  P.clf_w    = (const float*)d_in[28];  P.clf_b    = (const float*)d_in[29];
  P.out      = (float*)d_out;

  dim3 grid(NB / EPB), block(256);
  if (ws_size >= (size_t)WS_REQ_BYTES) {
    u16* ws = (u16*)d_ws;
    hipLaunchKernelGGL(OptimusPrime_prep, dim3(2), dim3(256), 0, stream, P, ws);
    hipLaunchKernelGGL(OptimusPrime_kernel<true>, grid, block, 0, stream, P, (const u16*)ws);
  } else {
    hipLaunchKernelGGL(OptimusPrime_kernel<false>, grid, block, 0, stream, P, (const u16*)nullptr);
  }
}

// Round 8
// 946.544 us; speedup vs baseline: 1.6529x; 1.4927x over previous
//
#include <hip/hip_runtime.h>

#define NB    131072
#define EPB   8      // batch elements per block
#define NTILE 6      // M-tiles: 2 tokens x 8 elems = 16 rows
#define SEQP  12     // 11 tokens + 1 pad
#define SXW   36     // sX row stride (f32)
#define SQW2  66     // sQ row stride (u32): q/ctx packed [0..31], k bf16 [32..47], v bf16 [48..63], pad
                     // FFN phase: h bf16 occupies u16 cols [0..127] of the same row

// ws layout (u16 units), per transformer block tb (stride WS_U16_PER_TB):
//   qkv hi @0      [6][64][8]   qkv lo @3072
//   wo  hi @6144   [2][64][8]   wo  lo @7168
//   w1  hi @8192   [8][64][8]   w1  lo @12288
//   w2  hi @16384  [4][2][64][8] w2 lo @20480
#define WS_U16_PER_TB 24576
#define WS_REQ_BYTES  (2 * WS_U16_PER_TB * 2)   // 98304 B

typedef short    bf16x8 __attribute__((ext_vector_type(8)));
typedef float    f32x4  __attribute__((ext_vector_type(4)));
typedef unsigned u32x8  __attribute__((ext_vector_type(8)));
typedef unsigned short u16;

struct Params {
  const float *x, *w_feat, *b_feat, *cls;
  const float *in_w[2], *in_b[2], *out_w[2], *out_b[2];
  const float *ln_a_g[2], *ln_a_b[2];
  const float *w1[2], *b1[2], *w2[2], *b2[2];
  const float *ln_b_g[2], *ln_b_b[2];
  const float *clf_w, *clf_b;
  float *out;
};

__device__ __forceinline__ float bf2f(u16 h){ return __uint_as_float(((unsigned)h)<<16); }
__device__ __forceinline__ u16 f2bf(float f){
  unsigned u = __float_as_uint(f);
  u += 0x7fffu + ((u>>16)&1u);          // RNE
  return (u16)(u>>16);
}
// truncation split: a ~= hi + lo, residual <= 2^-16 |a|
__device__ __forceinline__ void split8t(const float* p, bf16x8& hi, bf16x8& lo){
  #pragma unroll
  for (int j = 0; j < 8; ++j) {
    float a = p[j];
    unsigned u = __float_as_uint(a);
    hi[j] = (short)(u >> 16);
    float r = a - __uint_as_float(u & 0xffff0000u);
    lo[j] = (short)(__float_as_uint(r) >> 16);
  }
}
// pack f32 -> (hi16<<16)|lo16 in one u32
__device__ __forceinline__ unsigned packsplit(float a){
  unsigned u  = __float_as_uint(a);
  unsigned uh = u & 0xffff0000u;
  float    r  = a - __uint_as_float(uh);
  return uh | (__float_as_uint(r) >> 16);
}
__device__ __forceinline__ float unpack_f32(unsigned p){
  return __uint_as_float(p & 0xffff0000u) + __uint_as_float(p << 16);
}
__device__ __forceinline__ void frag_from_packed(u32x8 p, bf16x8& hi, bf16x8& lo){
  #pragma unroll
  for (int j = 0; j < 8; ++j) { hi[j] = (short)(p[j] >> 16); lo[j] = (short)(p[j] & 0xffffu); }
}
// RNE split (weights fallback path only)
__device__ __forceinline__ void split8(const float* p, bf16x8& hi, bf16x8& lo){
  #pragma unroll
  for (int j = 0; j < 8; ++j) {
    float a = p[j];
    u16 h = f2bf(a);
    hi[j] = (short)h;
    lo[j] = (short)f2bf(a - bf2f(h));
  }
}
// split-precision MFMA: acc += A*B, A=ah+al, B=bh+bl (drops al*bl ~ 2^-17)
__device__ __forceinline__ f32x4 mfma3(bf16x8 ah, bf16x8 al, bf16x8 bh, bf16x8 bl, f32x4 acc){
  acc = __builtin_amdgcn_mfma_f32_16x16x32_bf16(ah, bl, acc, 0,0,0);
  acc = __builtin_amdgcn_mfma_f32_16x16x32_bf16(al, bh, acc, 0,0,0);
  acc = __builtin_amdgcn_mfma_f32_16x16x32_bf16(ah, bh, acc, 0,0,0);
  return acc;
}
// A exact bf16, B split: acc += A*(bh+bl)
__device__ __forceinline__ f32x4 mfma2(bf16x8 a, bf16x8 bh, bf16x8 bl, f32x4 acc){
  acc = __builtin_amdgcn_mfma_f32_16x16x32_bf16(a, bl, acc, 0,0,0);
  acc = __builtin_amdgcn_mfma_f32_16x16x32_bf16(a, bh, acc, 0,0,0);
  return acc;
}
__device__ __forceinline__ bf16x8 ld8(const u16* p){ return *reinterpret_cast<const bf16x8*>(p); }
// tanh-form GELU (max abs err ~5e-4 vs exact erf form)
__device__ __forceinline__ float gelu_fast(float v){
  float y = 0.7978845608028654f * v * (1.f + 0.044715f * v * v);
  float e = __expf(2.f * y);
  float th = 1.f - 2.f * __builtin_amdgcn_rcpf(e + 1.f);
  return 0.5f * v * (1.f + th);
}

// ---------- prep: pre-split weights into per-lane B-fragment layout ----------
__global__ void OptimusPrime_prep(Params P, u16* ws)
{
  const int tb = blockIdx.x;
  u16* b = ws + tb * WS_U16_PER_TB;
  for (int idx = threadIdx.x; idx < 12288; idx += 256) {
    float v; int hiOff, loOff;
    if (idx < 3072) {                       // qkv  [6][64][8], K=32
      int nt = idx >> 9, lane = (idx >> 3) & 63, j = idx & 7;
      v = P.in_w[tb][(nt*16 + (lane&15))*32 + (lane>>4)*8 + j];
      hiOff = idx; loOff = 3072 + idx;
    } else if (idx < 4096) {                // wo   [2][64][8], K=32
      int m = idx - 3072;
      int nt = m >> 9, lane = (m >> 3) & 63, j = m & 7;
      v = P.out_w[tb][(nt*16 + (lane&15))*32 + (lane>>4)*8 + j];
      hiOff = 6144 + m; loOff = 7168 + m;
    } else if (idx < 8192) {                // w1   [8][64][8], K=32
      int m = idx - 4096;
      int nt = m >> 9, lane = (m >> 3) & 63, j = m & 7;
      v = P.w1[tb][(nt*16 + (lane&15))*32 + (lane>>4)*8 + j];
      hiOff = 8192 + m; loOff = 12288 + m;
    } else {                                // w2   [4][2][64][8], K=128
      int m = idx - 8192;
      int kt = m >> 10, nt = (m >> 9) & 1, lane = (m >> 3) & 63, j = m & 7;
      v = P.w2[tb][(nt*16 + (lane&15))*128 + kt*32 + (lane>>4)*8 + j];
      hiOff = 16384 + m; loOff = 20480 + m;
    }
    u16 h = f2bf(v);
    b[hiOff] = h;
    b[loOff] = f2bf(v - bf2f(h));
  }
}

// MFMA 16x16x32 bf16 layouts:
//   A-frag: a[j] = A[m=lane&15][k=(lane>>4)*8+j]
//   B-frag: b[j] = B[k=(lane>>4)*8+j][n=lane&15]
//   C/D   : acc[r] = C[row=(lane>>4)*4+r][col=lane&15]
// M-tile t covers rows m in [0,16): token s = 2t + (m>>3), elem e = m&7.

template<bool WS>
__global__ __launch_bounds__(256, 3)   // 3 waves/EU = ~168 unified VGPR cap; phase-3 split into
                                       // wo/w1/w2 sub-passes keeps peak live <~110 (rnd6/7: monolithic
                                       // phase-3 needs ~190 -> 2.6GB scratch spill)
void OptimusPrime_kernel(Params P, const u16* __restrict__ ws)
{
  __shared__ float    sX[SEQP][EPB][SXW];   // 13824 B : residual stream (f32)
  __shared__ unsigned sQ[SEQP][EPB][SQW2];  // 25344 B : packed q/ctx + bf16 k,v ; FFN h bf16

  const int tid  = threadIdx.x;
  const int w    = tid >> 6;
  const int lane = tid & 63;
  const int quad = lane >> 4;
  const int l16  = lane & 15;
  const int kq   = quad * 8;
  const int base = blockIdx.x * EPB;

  const int sA  = (l16 >> 3);
  const int eA  = (l16 & 7);
  const int sC  = (quad >> 1);
  const int eC0 = (quad & 1) * 4;

  // ---------- embed ----------
  for (int i = tid; i < SEQP*EPB*32; i += 256) {
    int d = i & 31, e = (i >> 5) & 7, s = i >> 8;
    float v;
    if (s == 0 || s == 11) v = P.cls[d];
    else v = P.x[(base+e)*10 + (s-1)] * P.w_feat[(s-1)*32 + d] + P.b_feat[(s-1)*32 + d];
    sX[s][e][d] = v;
  }
  __syncthreads();

  for (int tb = 0; tb < 2; ++tb) {
    const u16* wsb = WS ? (ws + tb * WS_U16_PER_TB) : nullptr;

    // ---------- QKV projection ----------
    {
      bf16x8 bh[6], bl[6]; float bias[6];
      #pragma unroll
      for (int nt = 0; nt < 6; ++nt) {
        if (WS) {
          bh[nt] = ld8(wsb + (nt*64 + lane)*8);
          bl[nt] = ld8(wsb + 3072 + (nt*64 + lane)*8);
        } else {
          split8(P.in_w[tb] + (nt*16 + l16)*32 + kq, bh[nt], bl[nt]);
        }
        bias[nt] = P.in_b[tb][nt*16 + l16];
      }
      for (int t = w; t < NTILE; t += 4) {
        bf16x8 ah, al; split8t(&sX[2*t + sA][eA][kq], ah, al);
        #pragma unroll
        for (int nt = 0; nt < 6; ++nt) {
          f32x4 acc = {0.f,0.f,0.f,0.f};
          acc = mfma3(ah, al, bh[nt], bl[nt], acc);
          #pragma unroll
          for (int r = 0; r < 4; ++r) {
            float vv = acc[r] + bias[nt];
            unsigned* qrow = &sQ[2*t + sC][eC0 + r][0];
            if (nt < 2) {
              qrow[nt*16 + l16] = packsplit(vv);                 // q packed
            } else if (nt < 4) {
              ((u16*)qrow)[64 + (nt-2)*16 + l16] = f2bf(vv);     // k bf16
            } else {
              ((u16*)qrow)[96 + (nt-4)*16 + l16] = f2bf(vv);     // v bf16
            }
          }
        }
      }
    }
    __syncthreads();

    // ---------- attention ----------
    {
      const int e = tid >> 5, hh = (tid >> 3) & 3, qs = tid & 7;
      for (int qi = qs; qi < 11; qi += 8) {
        u32x8 qp = *reinterpret_cast<const u32x8*>(&sQ[qi][e][hh*8]);
        float qf[8];
        #pragma unroll
        for (int j = 0; j < 8; ++j) qf[j] = unpack_f32(qp[j]) * 0.35355339059f;  // 1/sqrt(8)
        float sc[11]; float l = 0.f;
        for (int ki = 0; ki < 11; ++ki) {
          const u16* rk = (const u16*)&sQ[ki][e][0];
          bf16x8 kv = ld8(rk + 64 + hh*8);
          float s = 0.f;
          #pragma unroll
          for (int j = 0; j < 8; ++j) s += qf[j] * bf2f((u16)kv[j]);
          sc[ki] = __expf(s);            // scores O(1): no max-subtraction needed
          l += sc[ki];
        }
        float inv = __builtin_amdgcn_rcpf(l);
        float cx[8] = {0,0,0,0,0,0,0,0};
        for (int ki = 0; ki < 11; ++ki) {
          const u16* rv = (const u16*)&sQ[ki][e][0];
          bf16x8 vv = ld8(rv + 96 + hh*8);
          float p = sc[ki];
          #pragma unroll
          for (int j = 0; j < 8; ++j) cx[j] += p * bf2f((u16)vv[j]);
        }
        unsigned* wq = &sQ[qi][e][hh*8];
        #pragma unroll
        for (int j = 0; j < 8; ++j) wq[j] = packsplit(cx[j] * inv);   // ctx -> q slot, packed
      }
    }
    __syncthreads();

    // ---------- P3a: out-proj + LN_a (only wo live) ----------
    {
      bf16x8 woh[2], wol[2]; float ob[2], lag[2], lab[2];
      #pragma unroll
      for (int nt = 0; nt < 2; ++nt) {
        if (WS) {
          woh[nt] = ld8(wsb + 6144 + (nt*64 + lane)*8);
          wol[nt] = ld8(wsb + 7168 + (nt*64 + lane)*8);
        } else {
          split8(P.out_w[tb] + (nt*16 + l16)*32 + kq, woh[nt], wol[nt]);
        }
        ob[nt]  = P.out_b[tb][nt*16 + l16];
        lag[nt] = P.ln_a_g[tb][nt*16 + l16]; lab[nt] = P.ln_a_b[tb][nt*16 + l16];
      }
      for (int t = w; t < NTILE; t += 4) {
        u32x8 cp = *reinterpret_cast<const u32x8*>(&sQ[2*t + sA][eA][kq]);
        bf16x8 ah, al; frag_from_packed(cp, ah, al);
        float tt[2][4];
        #pragma unroll
        for (int nt = 0; nt < 2; ++nt) {
          f32x4 acc = {0.f,0.f,0.f,0.f};
          acc = mfma3(ah, al, woh[nt], wol[nt], acc);
          #pragma unroll
          for (int r = 0; r < 4; ++r)
            tt[nt][r] = acc[r] + ob[nt] + sX[2*t + sC][eC0 + r][nt*16 + l16];  // + residual
        }
        #pragma unroll
        for (int r = 0; r < 4; ++r) {
          float s1 = tt[0][r] + tt[1][r];
          float s2 = tt[0][r]*tt[0][r] + tt[1][r]*tt[1][r];
          #pragma unroll
          for (int mk = 1; mk < 16; mk <<= 1) { s1 += __shfl_xor(s1, mk); s2 += __shfl_xor(s2, mk); }
          float mu  = s1 * (1.f/32.f);
          float var = fmaxf(s2 * (1.f/32.f) - mu*mu, 0.f);
          float rs  = rsqrtf(var + 1e-5f);
          #pragma unroll
          for (int nt = 0; nt < 2; ++nt) {
            float y = (tt[nt][r] - mu)*rs*lag[nt] + lab[nt];
            sX[2*t + sC][eC0 + r][nt*16 + l16] = y;
          }
        }
      }
    }
    __builtin_amdgcn_sched_barrier(0);

    // ---------- P3b: FFN1 + GELU -> h bf16 (only w1 live) ----------
    // h[feature f] stored as bf16 in u16 cols [0..127] of own tile rows (overwrites dead ctx/k/v)
    {
      bf16x8 w1h[8], w1l[8]; float b1v[8];
      #pragma unroll
      for (int f8 = 0; f8 < 8; ++f8) {
        if (WS) {
          w1h[f8] = ld8(wsb + 8192  + (f8*64 + lane)*8);
          w1l[f8] = ld8(wsb + 12288 + (f8*64 + lane)*8);
        } else {
          split8(P.w1[tb] + (f8*16 + l16)*32 + kq, w1h[f8], w1l[f8]);
        }
        b1v[f8] = P.b1[tb][f8*16 + l16];
      }
      for (int t = w; t < NTILE; t += 4) {
        bf16x8 xh, xl; split8t(&sX[2*t + sA][eA][kq], xh, xl);
        #pragma unroll
        for (int fi = 0; fi < 8; ++fi) {
          f32x4 acc = {0.f,0.f,0.f,0.f};
          acc = mfma3(xh, xl, w1h[fi], w1l[fi], acc);
          #pragma unroll
          for (int r = 0; r < 4; ++r) {
            float v = acc[r] + b1v[fi];
            ((u16*)&sQ[2*t + sC][eC0 + r][0])[fi*16 + l16] = f2bf(gelu_fast(v));
          }
        }
      }
    }
    __builtin_amdgcn_sched_barrier(0);

    // ---------- P3c: FFN2 + residual + LN_b (only w2 live) ----------
    {
      bf16x8 w2h[4][2], w2l[4][2]; float b2v[2], lbg[2], lbb[2];
      #pragma unroll
      for (int kt = 0; kt < 4; ++kt)
        #pragma unroll
        for (int nt = 0; nt < 2; ++nt) {
          if (WS) {
            w2h[kt][nt] = ld8(wsb + 16384 + ((kt*2 + nt)*64 + lane)*8);
            w2l[kt][nt] = ld8(wsb + 20480 + ((kt*2 + nt)*64 + lane)*8);
          } else {
            split8(P.w2[tb] + (nt*16 + l16)*128 + kt*32 + kq, w2h[kt][nt], w2l[kt][nt]);
          }
        }
      #pragma unroll
      for (int nt = 0; nt < 2; ++nt) {
        b2v[nt] = P.b2[tb][nt*16 + l16];
        lbg[nt] = P.ln_b_g[tb][nt*16 + l16]; lbb[nt] = P.ln_b_b[tb][nt*16 + l16];
      }
      for (int t = w; t < NTILE; t += 4) {
        f32x4 ca0 = {0.f,0.f,0.f,0.f}, ca1 = {0.f,0.f,0.f,0.f};
        #pragma unroll
        for (int kt = 0; kt < 4; ++kt) {
          bf16x8 hf = ld8((const u16*)&sQ[2*t + sA][eA][0] + kt*32 + kq);
          ca0 = mfma2(hf, w2h[kt][0], w2l[kt][0], ca0);
          ca1 = mfma2(hf, w2h[kt][1], w2l[kt][1], ca1);
        }
        float tt[2][4];
        #pragma unroll
        for (int nt = 0; nt < 2; ++nt) {
          f32x4 ca = nt ? ca1 : ca0;
          #pragma unroll
          for (int r = 0; r < 4; ++r)
            tt[nt][r] = ca[r] + b2v[nt] + sX[2*t + sC][eC0 + r][nt*16 + l16];  // + residual
        }
        #pragma unroll
        for (int r = 0; r < 4; ++r) {
          float s1 = tt[0][r] + tt[1][r];
          float s2 = tt[0][r]*tt[0][r] + tt[1][r]*tt[1][r];
          #pragma unroll
          for (int mk = 1; mk < 16; mk <<= 1) { s1 += __shfl_xor(s1, mk); s2 += __shfl_xor(s2, mk); }
          float mu  = s1 * (1.f/32.f);
          float var = fmaxf(s2 * (1.f/32.f) - mu*mu, 0.f);
          float rs  = rsqrtf(var + 1e-5f);
          #pragma unroll
          for (int nt = 0; nt < 2; ++nt) {
            float y = (tt[nt][r] - mu)*rs*lbg[nt] + lbb[nt];
            sX[2*t + sC][eC0 + r][nt*16 + l16] = y;
          }
        }
      }
    }
    __syncthreads();
  }

  // ---------- classifier: out[b] = sX[0][e][:] . clf_w + clf_b ----------
  if (w == 0) {
    int e = lane >> 3, dq = lane & 7;
    float p = 0.f;
    #pragma unroll
    for (int j = 0; j < 4; ++j)
      p += sX[0][e][dq*4 + j] * P.clf_w[dq*4 + j];
    p += __shfl_xor(p, 1);
    p += __shfl_xor(p, 2);
    p += __shfl_xor(p, 4);
    if (dq == 0)
      P.out[base + e] = p + P.clf_b[0];
  }
}

extern "C" void kernel_launch(void* const* d_in, const int* in_sizes, int n_in,
                              void* d_out, int out_size, void* d_ws, size_t ws_size,
                              hipStream_t stream)
{
  Params P;
  P.x        = (const float*)d_in[0];
  P.w_feat   = (const float*)d_in[1];
  P.b_feat   = (const float*)d_in[2];
  P.cls      = (const float*)d_in[3];
  P.in_w[0]  = (const float*)d_in[4];   P.in_b[0]  = (const float*)d_in[5];
  P.out_w[0] = (const float*)d_in[6];   P.out_b[0] = (const float*)d_in[7];
  P.ln_a_g[0]= (const float*)d_in[8];   P.ln_a_b[0]= (const float*)d_in[9];
  P.w1[0]    = (const float*)d_in[10];  P.b1[0]    = (const float*)d_in[11];
  P.w2[0]    = (const float*)d_in[12];  P.b2[0]    = (const float*)d_in[13];
  P.ln_b_g[0]= (const float*)d_in[14];  P.ln_b_b[0]= (const float*)d_in[15];
  P.in_w[1]  = (const float*)d_in[16];  P.in_b[1]  = (const float*)d_in[17];
  P.out_w[1] = (const float*)d_in[18];  P.out_b[1] = (const float*)d_in[19];
  P.ln_a_g[1]= (const float*)d_in[20];  P.ln_a_b[1]= (const float*)d_in[21];
  P.w1[1]    = (const float*)d_in[22];  P.b1[1]    = (const float*)d_in[23];
  P.w2[1]    = (const float*)d_in[24];  P.b2[1]    = (const float*)d_in[25];
  P.ln_b_g[1]= (const float*)d_in[26];  P.ln_b_b[1]= (const float*)d_in[27];
  P.clf_w    = (const float*)d_in[28];  P.clf_b    = (const float*)d_in[29];
  P.out      = (float*)d_out;

  dim3 grid(NB / EPB), block(256);
  if (ws_size >= (size_t)WS_REQ_BYTES) {
    u16* ws = (u16*)d_ws;
    hipLaunchKernelGGL(OptimusPrime_prep, dim3(2), dim3(256), 0, stream, P, ws);
    hipLaunchKernelGGL(OptimusPrime_kernel<true>, grid, block, 0, stream, P, (const u16*)ws);
  } else {
    hipLaunchKernelGGL(OptimusPrime_kernel<false>, grid, block, 0, stream, P, (const u16*)nullptr);
  }
}